// Round 3
// baseline (544.571 us; speedup 1.0000x reference)
//
#include <hip/hip_runtime.h>
#include <hip/hip_bf16.h>

// out = lambda * ||F^T F_star||_F^2,  F,F* fp32 [16384, 2048]
#define N_ROWS 16384
#define D_DIM  2048
#define SPLITK 4
#define NS     (N_ROWS / 32)     // 512 k-steps of 32
#define NP     (D_DIM / 128)     // 16 panels of 128 rows
#define NSS    (NS / SPLITK)     // 128 k-steps per split
#define NKT    (NSS / 2)         // 64 K-tiles (BK=64) per block

// Packed operand layout (bf16): chunk(m_panel, k_step) = 8192 B contiguous at
// ushort offset (m_panel*NS + k_step)*4096. Within a chunk, subtile tt (16 rows):
// offset(m,k) = tt*512 + lane*8 + j for lane = (k>>3)<<4 | (m&15): the MFMA
// A/B fragment image. All LDS reads are linear 16B/lane -> conflict-free.

typedef __attribute__((ext_vector_type(8))) short short8;        // 8 bf16 (4 VGPRs)
typedef __attribute__((ext_vector_type(4))) float f32x4;         // MFMA acc
typedef __attribute__((ext_vector_type(8))) unsigned short ushort8;
typedef __attribute__((ext_vector_type(4))) unsigned short ushort4v;

#define GPTR(p) ((const __attribute__((address_space(1))) void*)(p))
#define LPTR(p) ((__attribute__((address_space(3))) void*)(p))

__device__ __forceinline__ unsigned short f2bf(float x) {
  __hip_bfloat16 b = __float2bfloat16(x);
  return *reinterpret_cast<unsigned short*>(&b);
}
__device__ __forceinline__ float bf2f(unsigned short u) {
  unsigned int v = ((unsigned int)u) << 16;
  return *reinterpret_cast<float*>(&v);
}

// ---------- Pass 1: fp32[N][D] -> packed bf16 fragment image ----------
// 2 col-panels per iteration: each row-visit reads 1 KB contiguous (was 512 B),
// halving DRAM page re-opens. Grid 256 x 2, contiguous 512 KB region per block.
__global__ void __launch_bounds__(256) transpose_pack(
    const float* __restrict__ F, const float* __restrict__ Fs,
    unsigned short* __restrict__ Fb, unsigned short* __restrict__ Fsb) {
  const float* src = blockIdx.y ? Fs : F;
  unsigned short* dst = blockIdx.y ? Fsb : Fb;
  const int t = threadIdx.x;
  const int kb0 = blockIdx.x * 64;               // 64 k-rows per block

  const int mg   = t & 31;                       // m-group within panel: cols mg*4..+3
  const int koct = (t >> 5) & 3;                 // k-octet within a 32-k chunk
  const int c    = t >> 7;                       // which of the 2 chunks
  const int krow = kb0 + c * 32 + koct * 8;
  const int ks   = blockIdx.x * 2 + c;           // global k-step of chunk c

  const float* srow = &src[(size_t)krow * D_DIM + mg * 4];
  unsigned short* obase = dst + (size_t)ks * 4096
                        + (size_t)(mg >> 2) * 512 + (size_t)koct * 128
                        + (size_t)(mg & 3) * 32;

#define STOREP(R, MT) do {                                                     \
    const float* _rp = (const float*)(R);                                      \
    unsigned short* _b = obase + (size_t)(MT) * (NS * 4096);                   \
    _Pragma("unroll") for (int i = 0; i < 4; ++i) {                            \
      ushort8 _o;                                                              \
      _Pragma("unroll") for (int j = 0; j < 8; ++j) _o[j] = f2bf(_rp[j*4+i]);  \
      *(ushort8*)&_b[i * 8] = _o;                                              \
    }                                                                          \
  } while (0)

  for (int mt = 0; mt < NP; mt += 2) {
    float4 r0[8], r1[8];
#pragma unroll
    for (int j = 0; j < 8; ++j) {                // adjacent 512B pairs -> 1KB/row visit
      r0[j] = *(const float4*)&srow[(size_t)j * D_DIM + mt * 128];
      r1[j] = *(const float4*)&srow[(size_t)j * D_DIM + mt * 128 + 128];
    }
    STOREP(r0, mt);
    STOREP(r1, mt + 1);
  }
#undef STOREP
}

// ---------- Pass 2: 256x256 tile, BK=64, 8 waves, 2-barrier-per-tile schedule ----------
// LDS 128 KB (ushort units): A buf b panel p  at  b*16384 + p*8192
//                            B buf b panel q  at  32768 + b*16384 + q*8192
// Per K-tile T (buf B=T&1):
//   stage A(T+1) -> buf^1            (issued at tile start; that region's last
//                                     reader finished before the previous end-barrier)
//   issue all 24 ds_reads (A0-7 x2sl, B0-1, B2-3)
//   MFMA half 1: i0-7 x j0-1 (32)    -- overlaps read drain (compiler-counted lgkmcnt)
//   lgkmcnt(0); s_barrier            -- all waves done reading => B(T) region free
//   stage B(T+2) -> buf              (WAR-safe after barrier)
//   MFMA half 2: i0-7 x j2-3 (32)    -- register-only, overlaps B staging
//   vmcnt(4); s_barrier              -- A(T+1)+B(T+1) landed, B(T+2) x4 still flying
// vmcnt ledger: outstanding at T's end-wait = B(T+1)x4 + A(T+1)x4 + B(T+2)x4 = 12;
// vmcnt(4) drains the first 8 -> tile T+1's operands are all resident.
__global__ void __launch_bounds__(512, 2) gemm_packed(
    const unsigned short* __restrict__ Fb, const unsigned short* __restrict__ Fsb,
    unsigned short* __restrict__ Cpart) {
  __shared__ unsigned short lds[65536];          // 128 KB
  const int tid = threadIdx.x;
  const int w = tid >> 6, lane = tid & 63;
  const int wm = w >> 2, wn = w & 3;             // 2x4 waves, each owns 128x64 of C

  // XCD-aware bijective swizzle: physical linear id round-robins XCDs; remap so
  // each XCD owns 32 contiguous logical blocks = 4 complete by-rows (A reuse in L2).
  const int lin = blockIdx.x + (blockIdx.y << 3) + ((int)blockIdx.z << 6); // 0..255
  const int l   = (lin & 7) * 32 + (lin >> 3);
  const int bx = l & 7, by = (l >> 3) & 7, z = l >> 6;

  const size_t kbase = (size_t)z * NSS * 4096;   // this split's k-range (ushorts)
  size_t aSrc0 = ((size_t)(by * 2 + 0) * NS) * 4096 + kbase + (size_t)w * 1024 + lane * 8;
  size_t aSrc1 = ((size_t)(by * 2 + 1) * NS) * 4096 + kbase + (size_t)w * 1024 + lane * 8;
  size_t bSrc0 = ((size_t)(bx * 2 + 0) * NS) * 4096 + kbase + (size_t)w * 1024 + lane * 8;
  size_t bSrc1 = ((size_t)(bx * 2 + 1) * NS) * 4096 + kbase + (size_t)w * 1024 + lane * 8;

  const int aRd = wm * 8192 + lane * 8;                          // A frag base (ushorts)
  const int bRd = (wn >> 1) * 8192 + (wn & 1) * 2048 + lane * 8; // B frag base

#define STAGE_A(KT, P, BUF) do {                                               \
    int _kt = (KT); if (_kt >= NKT) _kt -= NKT;                                \
    const unsigned short* _s = Fb + (P ? aSrc1 : aSrc0) + (size_t)_kt * 8192;  \
    unsigned short* _d = &lds[(BUF) * 16384 + (P) * 8192 + w * 1024];          \
    __builtin_amdgcn_global_load_lds(GPTR(_s),       LPTR(_d),       16, 0, 0);\
    __builtin_amdgcn_global_load_lds(GPTR(_s + 512), LPTR(_d + 512), 16, 0, 0);\
  } while (0)
#define STAGE_B(KT, Q, BUF) do {                                               \
    int _kt = (KT); if (_kt >= NKT) _kt -= NKT;                                \
    const unsigned short* _s = Fsb + (Q ? bSrc1 : bSrc0) + (size_t)_kt * 8192; \
    unsigned short* _d = &lds[32768 + (BUF) * 16384 + (Q) * 8192 + w * 1024];  \
    __builtin_amdgcn_global_load_lds(GPTR(_s),       LPTR(_d),       16, 0, 0);\
    __builtin_amdgcn_global_load_lds(GPTR(_s + 512), LPTR(_d + 512), 16, 0, 0);\
  } while (0)
#define LDA(DST, BUF, I, SL) (DST) = *(const short8*)&lds[(BUF) * 16384 + aRd + (SL) * 4096 + (I) * 512]
#define LDB(DST, BUF, J, SL) (DST) = *(const short8*)&lds[32768 + (BUF) * 16384 + bRd + (SL) * 4096 + (J) * 512]

  f32x4 acc[8][4];
#pragma unroll
  for (int i = 0; i < 8; ++i)
#pragma unroll
    for (int j = 0; j < 4; ++j) acc[i][j] = 0.f;

  short8 aR[8][2], bLo[2][2], bHi[2][2];

  // prologue: tile 0 (A+B) into buf0, tile 1's B into buf1 (A(1) staged in tile 0)
  STAGE_A(0, 0, 0); STAGE_A(0, 1, 0);
  STAGE_B(0, 0, 0); STAGE_B(0, 1, 0);
  STAGE_B(1, 0, 1); STAGE_B(1, 1, 1);
  asm volatile("s_waitcnt vmcnt(4)" ::: "memory");   // tile 0 landed; B(1) may fly
  __builtin_amdgcn_s_barrier();
  __builtin_amdgcn_sched_barrier(0);

#define TILE(T, B) do {                                                        \
    STAGE_A((T) + 1, 0, (B) ^ 1);                                              \
    STAGE_A((T) + 1, 1, (B) ^ 1);                                              \
    _Pragma("unroll") for (int i = 0; i < 8; ++i) {                            \
      LDA(aR[i][0], B, i, 0); LDA(aR[i][1], B, i, 1); }                        \
    _Pragma("unroll") for (int j = 0; j < 2; ++j) {                            \
      LDB(bLo[j][0], B, j, 0); LDB(bLo[j][1], B, j, 1); }                      \
    _Pragma("unroll") for (int j = 0; j < 2; ++j) {                            \
      LDB(bHi[j][0], B, 2 + j, 0); LDB(bHi[j][1], B, 2 + j, 1); }              \
    __builtin_amdgcn_s_setprio(1);                                             \
    _Pragma("unroll") for (int sl = 0; sl < 2; ++sl)                           \
      _Pragma("unroll") for (int i = 0; i < 8; ++i)                            \
        _Pragma("unroll") for (int j = 0; j < 2; ++j)                          \
          acc[i][j] = __builtin_amdgcn_mfma_f32_16x16x32_bf16(aR[i][sl], bLo[j][sl], acc[i][j], 0, 0, 0); \
    __builtin_amdgcn_s_setprio(0);                                             \
    asm volatile("s_waitcnt lgkmcnt(0)" ::: "memory");                         \
    __builtin_amdgcn_s_barrier();                                              \
    __builtin_amdgcn_sched_barrier(0);                                         \
    STAGE_B((T) + 2, 0, B);                                                    \
    STAGE_B((T) + 2, 1, B);                                                    \
    __builtin_amdgcn_s_setprio(1);                                             \
    _Pragma("unroll") for (int sl = 0; sl < 2; ++sl)                           \
      _Pragma("unroll") for (int i = 0; i < 8; ++i)                            \
        _Pragma("unroll") for (int j = 0; j < 2; ++j)                          \
          acc[i][2 + j] = __builtin_amdgcn_mfma_f32_16x16x32_bf16(aR[i][sl], bHi[j][sl], acc[i][2 + j], 0, 0, 0); \
    __builtin_amdgcn_s_setprio(0);                                             \
    asm volatile("s_waitcnt vmcnt(4)" ::: "memory");                           \
    __builtin_amdgcn_s_barrier();                                              \
    __builtin_amdgcn_sched_barrier(0);                                         \
  } while (0)

  for (int t = 0; t < NKT; t += 2) {
    TILE(t, 0);
    TILE(t + 1, 1);
  }

  // Frobenius norm is layout-invariant: dump partials flat, coalesced, bf16.
  unsigned short* cp = Cpart + (size_t)z * (D_DIM * D_DIM)
                     + (size_t)(by * 8 + bx) * 65536 + w * 8192 + lane * 4;
#pragma unroll
  for (int i = 0; i < 8; ++i)
#pragma unroll
    for (int j = 0; j < 4; ++j) {
      ushort4v o;
#pragma unroll
      for (int r = 0; r < 4; ++r) o[r] = f2bf(acc[i][j][r]);
      *(ushort4v*)&cp[(i * 4 + j) * 256] = o;
    }
#undef STAGE_A
#undef STAGE_B
#undef LDA
#undef LDB
#undef TILE
}

// ---------- Pass 3: sum bf16 split partials, square, reduce ----------
__global__ void __launch_bounds__(256) reduce_squares(
    const unsigned short* __restrict__ Cpart, const float* __restrict__ lam,
    float* __restrict__ out) {
  const int NQ = (D_DIM * D_DIM) / 8;            // ushort8 chunks per split
  const ushort8* c = (const ushort8*)Cpart;
  float s = 0.f;
  for (int idx = blockIdx.x * 256 + threadIdx.x; idx < NQ; idx += gridDim.x * 256) {
    float v[8];
#pragma unroll
    for (int j = 0; j < 8; ++j) v[j] = 0.f;
#pragma unroll
    for (int z = 0; z < SPLITK; ++z) {
      ushort8 u = c[(size_t)z * NQ + idx];
#pragma unroll
      for (int j = 0; j < 8; ++j) v[j] += bf2f(u[j]);
    }
#pragma unroll
    for (int j = 0; j < 8; ++j) s += v[j] * v[j];
  }
  for (int off = 32; off > 0; off >>= 1) s += __shfl_down(s, off, 64);
  __shared__ float red[4];
  const int wave = threadIdx.x >> 6, lane = threadIdx.x & 63;
  if (lane == 0) red[wave] = s;
  __syncthreads();
  if (threadIdx.x == 0) atomicAdd(out, (red[0] + red[1] + red[2] + red[3]) * lam[0]);
}

// ---------- Fallback (only if ws too small): correct, slow ----------
__global__ void __launch_bounds__(256) fallback_kernel(
    const float* __restrict__ F, const float* __restrict__ Fs,
    const float* __restrict__ lam, float* __restrict__ out) {
  __shared__ float sA[64][16], sB[64][16];
  const int d0 = blockIdx.y * 16, e0 = blockIdx.x * 16;
  const int t = threadIdx.x;
  const int td = t >> 4, te = t & 15;
  float s = 0.f;
  for (int k0 = 0; k0 < N_ROWS; k0 += 64) {
#pragma unroll
    for (int p = 0; p < 4; ++p) {
      const int k = (t >> 4) + p * 16;
      const int cc = t & 15;
      sA[k][cc] = F[(size_t)(k0 + k) * D_DIM + d0 + cc];
      sB[k][cc] = Fs[(size_t)(k0 + k) * D_DIM + e0 + cc];
    }
    __syncthreads();
#pragma unroll
    for (int kk = 0; kk < 64; ++kk) s += sA[kk][td] * sB[kk][te];
    __syncthreads();
  }
  float q = s * s;
  for (int off = 32; off > 0; off >>= 1) q += __shfl_down(q, off, 64);
  __shared__ float red[4];
  if ((t & 63) == 0) red[t >> 6] = q;
  __syncthreads();
  if (t == 0) atomicAdd(out, (red[0] + red[1] + red[2] + red[3]) * lam[0]);
}

extern "C" void kernel_launch(void* const* d_in, const int* in_sizes, int n_in,
                              void* d_out, int out_size, void* d_ws, size_t ws_size,
                              hipStream_t stream) {
  const float* F   = (const float*)d_in[0];
  const float* Fs  = (const float*)d_in[1];
  const float* lam = (const float*)d_in[2];
  float* out = (float*)d_out;
  hipMemsetAsync(d_out, 0, sizeof(float) * (size_t)out_size, stream);

  const size_t bf_bytes = (size_t)NP * NS * 8192;                 // 64 MB per packed matrix
  const size_t cpart_bytes = (size_t)SPLITK * D_DIM * D_DIM * 2;  // 32 MB (bf16 partials)
  const size_t need = 2 * bf_bytes + cpart_bytes;                 // 160 MB

  if (ws_size >= need) {
    unsigned short* Fb  = (unsigned short*)d_ws;
    unsigned short* Fsb = Fb + bf_bytes / 2;
    unsigned short* Cpart = (unsigned short*)((char*)d_ws + 2 * bf_bytes);
    transpose_pack<<<dim3(N_ROWS / 64, 2), 256, 0, stream>>>(F, Fs, Fb, Fsb);
    gemm_packed<<<dim3(8, 8, SPLITK), 512, 0, stream>>>(Fb, Fsb, Cpart);
    reduce_squares<<<dim3(1024), 256, 0, stream>>>(Cpart, lam, out);
  } else {
    fallback_kernel<<<dim3(128, 128), 256, 0, stream>>>(F, Fs, lam, out);
  }
}

// Round 4
// 435.035 us; speedup vs baseline: 1.2518x; 1.2518x over previous
//
#include <hip/hip_runtime.h>
#include <hip/hip_bf16.h>

// out = lambda * ||F^T F_star||_F^2,  F,F* fp32 [16384, 2048]
#define N_ROWS 16384
#define D_DIM  2048
#define SPLITK 4
#define NS     (N_ROWS / 32)     // 512 k-steps of 32
#define NP     (D_DIM / 128)     // 16 panels of 128 rows
#define NSS    (NS / SPLITK)     // 128 k-steps per split
#define NKT    (NSS / 2)         // 64 K-tiles (BK=64) per block

// Packed operand layout (bf16): chunk(m_panel, k_step) = 8192 B contiguous at
// ushort offset (m_panel*NS + k_step)*4096. Within a chunk, subtile tt (16 rows):
// offset(m,k) = tt*512 + lane*8 + j for lane = (k>>3)<<4 | (m&15): the MFMA
// A/B fragment image. All LDS reads are linear 16B/lane -> conflict-free.

typedef __attribute__((ext_vector_type(8))) short short8;        // 8 bf16 (4 VGPRs)
typedef __attribute__((ext_vector_type(4))) float f32x4;         // MFMA acc
typedef __attribute__((ext_vector_type(8))) unsigned short ushort8;
typedef __attribute__((ext_vector_type(4))) unsigned short ushort4v;

#define GPTR(p) ((const __attribute__((address_space(1))) void*)(p))
#define LPTR(p) ((__attribute__((address_space(3))) void*)(p))

__device__ __forceinline__ unsigned short f2bf(float x) {
  __hip_bfloat16 b = __float2bfloat16(x);
  return *reinterpret_cast<unsigned short*>(&b);
}
__device__ __forceinline__ float bf2f(unsigned short u) {
  unsigned int v = ((unsigned int)u) << 16;
  return *reinterpret_cast<float*>(&v);
}

// ---------- Pass 1: fp32[N][D] -> packed bf16 fragment image ----------
__global__ void __launch_bounds__(256) transpose_pack(
    const float* __restrict__ F, const float* __restrict__ Fs,
    unsigned short* __restrict__ Fb, unsigned short* __restrict__ Fsb) {
  const float* src = blockIdx.y ? Fs : F;
  unsigned short* dst = blockIdx.y ? Fsb : Fb;
  const int t = threadIdx.x;
  const int kb0 = blockIdx.x * 64;               // 64 k-rows per block

  const int mg   = t & 31;                       // m-group within panel: cols mg*4..+3
  const int koct = (t >> 5) & 3;                 // k-octet within a 32-k chunk
  const int c    = t >> 7;                       // which of the 2 chunks
  const int krow = kb0 + c * 32 + koct * 8;
  const int ks   = blockIdx.x * 2 + c;           // global k-step of chunk c

  const float* srow = &src[(size_t)krow * D_DIM + mg * 4];
  unsigned short* obase = dst + (size_t)ks * 4096
                        + (size_t)(mg >> 2) * 512 + (size_t)koct * 128
                        + (size_t)(mg & 3) * 32;

#define STOREP(R, MT) do {                                                     \
    const float* _rp = (const float*)(R);                                      \
    unsigned short* _b = obase + (size_t)(MT) * (NS * 4096);                   \
    _Pragma("unroll") for (int i = 0; i < 4; ++i) {                            \
      ushort8 _o;                                                              \
      _Pragma("unroll") for (int j = 0; j < 8; ++j) _o[j] = f2bf(_rp[j*4+i]);  \
      *(ushort8*)&_b[i * 8] = _o;                                              \
    }                                                                          \
  } while (0)

  for (int mt = 0; mt < NP; mt += 2) {
    float4 r0[8], r1[8];
#pragma unroll
    for (int j = 0; j < 8; ++j) {                // adjacent 512B pairs -> 1KB/row visit
      r0[j] = *(const float4*)&srow[(size_t)j * D_DIM + mt * 128];
      r1[j] = *(const float4*)&srow[(size_t)j * D_DIM + mt * 128 + 128];
    }
    STOREP(r0, mt);
    STOREP(r1, mt + 1);
  }
#undef STOREP
}

// ---------- Pass 2: 256x256 tile, BK=64, 8 waves, 2-barrier/tile, A-chunk pipelined ----------
// LDS 128 KB (ushort units): A buf b panel p at b*16384 + p*8192
//                            B buf b panel q at 32768 + b*16384 + q*8192
// Register budget (2 waves/SIMD => 256 unified/wave): acc 128 AGPR + bAll 32
// + aR dbuf 32 + addressing ~ round-2's 248. (Round 3's aR[8][2] = +32 => spill.)
//
// Per K-tile T (buf B=T&1):
//   STAGE_A(T+1)->buf^1                      (region's readers drained last tile)
//   LDB all 8 (B resident) ; LDA chunk0 (4)
//   for c=0..3: [LDA chunk c+1 (4)] ; MFMA chunk c (16)   <- reads lead MFMA by
//     one chunk; compiler inserts counted lgkmcnt (no forced drain)
//   lgkmcnt(0) ; barrier                     (B(T) fully consumed -> WAR safe)
//   STAGE_B(T+2)->buf
//   vmcnt(4) ; barrier                       (A(T+1),B(T+1) landed; B(T+2) flying)
// vmcnt ledger at T's wait: B(T+1)4 + A(T+1)4 + B(T+2)4 = 12 outstanding,
// vmcnt(4) drains first 8 -> tile T+1 operands resident. Wrapped indices at the
// tail are harmless reloads.
__global__ void __launch_bounds__(512, 2) gemm_packed(
    const unsigned short* __restrict__ Fb, const unsigned short* __restrict__ Fsb,
    unsigned short* __restrict__ Cpart) {
  __shared__ unsigned short lds[65536];          // 128 KB
  const int tid = threadIdx.x;
  const int w = tid >> 6, lane = tid & 63;
  const int wm = w >> 2, wn = w & 3;             // 2x4 waves, each owns 128x64 of C

  // XCD-aware bijective swizzle: each XCD gets 32 contiguous logical blocks =
  // 4 complete by-rows of one split (A panels + per-tile B slices stay in its L2).
  const int lin = blockIdx.x + (blockIdx.y << 3) + ((int)blockIdx.z << 6); // 0..255
  const int l   = (lin & 7) * 32 + (lin >> 3);
  const int bx = l & 7, by = (l >> 3) & 7, z = l >> 6;

  const size_t kbase = (size_t)z * NSS * 4096;   // this split's k-range (ushorts)
  size_t aSrc0 = ((size_t)(by * 2 + 0) * NS) * 4096 + kbase + (size_t)w * 1024 + lane * 8;
  size_t aSrc1 = ((size_t)(by * 2 + 1) * NS) * 4096 + kbase + (size_t)w * 1024 + lane * 8;
  size_t bSrc0 = ((size_t)(bx * 2 + 0) * NS) * 4096 + kbase + (size_t)w * 1024 + lane * 8;
  size_t bSrc1 = ((size_t)(bx * 2 + 1) * NS) * 4096 + kbase + (size_t)w * 1024 + lane * 8;

  const int aRd = wm * 8192 + lane * 8;                          // A frag base (ushorts)
  const int bRd = (wn >> 1) * 8192 + (wn & 1) * 2048 + lane * 8; // B frag base

#define STAGE_A(KT, P, BUF) do {                                               \
    int _kt = (KT); if (_kt >= NKT) _kt -= NKT;                                \
    const unsigned short* _s = Fb + (P ? aSrc1 : aSrc0) + (size_t)_kt * 8192;  \
    unsigned short* _d = &lds[(BUF) * 16384 + (P) * 8192 + w * 1024];          \
    __builtin_amdgcn_global_load_lds(GPTR(_s),       LPTR(_d),       16, 0, 0);\
    __builtin_amdgcn_global_load_lds(GPTR(_s + 512), LPTR(_d + 512), 16, 0, 0);\
  } while (0)
#define STAGE_B(KT, Q, BUF) do {                                               \
    int _kt = (KT); if (_kt >= NKT) _kt -= NKT;                                \
    const unsigned short* _s = Fsb + (Q ? bSrc1 : bSrc0) + (size_t)_kt * 8192; \
    unsigned short* _d = &lds[32768 + (BUF) * 16384 + (Q) * 8192 + w * 1024];  \
    __builtin_amdgcn_global_load_lds(GPTR(_s),       LPTR(_d),       16, 0, 0);\
    __builtin_amdgcn_global_load_lds(GPTR(_s + 512), LPTR(_d + 512), 16, 0, 0);\
  } while (0)
#define LDA(DST, BUF, I, SL) (DST) = *(const short8*)&lds[(BUF) * 16384 + aRd + (SL) * 4096 + (I) * 512]
#define LDB(DST, BUF, J, SL) (DST) = *(const short8*)&lds[32768 + (BUF) * 16384 + bRd + (SL) * 4096 + (J) * 512]

  f32x4 acc[8][4];
#pragma unroll
  for (int i = 0; i < 8; ++i)
#pragma unroll
    for (int j = 0; j < 4; ++j) acc[i][j] = 0.f;

  short8 bAll[4][2];        // B resident: 32 VGPRs
  short8 aR[2][2][2];       // A chunk double-buffer [buf][row][sl]: 32 VGPRs

  // prologue: tile 0 (A+B) into buf0, tile 1's B into buf1 (A(1) staged in tile 0)
  STAGE_A(0, 0, 0); STAGE_A(0, 1, 0);
  STAGE_B(0, 0, 0); STAGE_B(0, 1, 0);
  STAGE_B(1, 0, 1); STAGE_B(1, 1, 1);
  asm volatile("s_waitcnt vmcnt(4)" ::: "memory");   // tile 0 landed; B(1) may fly
  __builtin_amdgcn_s_barrier();
  asm volatile("" ::: "memory");

#define TILE(T, B) do {                                                        \
    STAGE_A((T) + 1, 0, (B) ^ 1);                                              \
    STAGE_A((T) + 1, 1, (B) ^ 1);                                              \
    _Pragma("unroll") for (int j = 0; j < 4; ++j) {                            \
      LDB(bAll[j][0], B, j, 0); LDB(bAll[j][1], B, j, 1); }                    \
    LDA(aR[0][0][0], B, 0, 0); LDA(aR[0][0][1], B, 0, 1);                      \
    LDA(aR[0][1][0], B, 1, 0); LDA(aR[0][1][1], B, 1, 1);                      \
    _Pragma("unroll") for (int c = 0; c < 4; ++c) {                            \
      if (c < 3) {                                                             \
        LDA(aR[(c + 1) & 1][0][0], B, 2 * c + 2, 0);                           \
        LDA(aR[(c + 1) & 1][0][1], B, 2 * c + 2, 1);                           \
        LDA(aR[(c + 1) & 1][1][0], B, 2 * c + 3, 0);                           \
        LDA(aR[(c + 1) & 1][1][1], B, 2 * c + 3, 1);                           \
      }                                                                        \
      __builtin_amdgcn_s_setprio(1);                                           \
      _Pragma("unroll") for (int sl = 0; sl < 2; ++sl)                         \
        _Pragma("unroll") for (int iw = 0; iw < 2; ++iw)                       \
          _Pragma("unroll") for (int j = 0; j < 4; ++j)                        \
            acc[2 * c + iw][j] = __builtin_amdgcn_mfma_f32_16x16x32_bf16(      \
                aR[c & 1][iw][sl], bAll[j][sl], acc[2 * c + iw][j], 0, 0, 0);  \
      __builtin_amdgcn_s_setprio(0);                                           \
    }                                                                          \
    asm volatile("s_waitcnt lgkmcnt(0)" ::: "memory");                         \
    __builtin_amdgcn_s_barrier();                                              \
    asm volatile("" ::: "memory");                                             \
    STAGE_B((T) + 2, 0, B);                                                    \
    STAGE_B((T) + 2, 1, B);                                                    \
    asm volatile("s_waitcnt vmcnt(4)" ::: "memory");                           \
    __builtin_amdgcn_s_barrier();                                              \
    asm volatile("" ::: "memory");                                             \
  } while (0)

  for (int t = 0; t < NKT; t += 2) {
    TILE(t, 0);
    TILE(t + 1, 1);
  }

  // Frobenius norm is layout-invariant: dump partials flat, coalesced, bf16.
  unsigned short* cp = Cpart + (size_t)z * (D_DIM * D_DIM)
                     + (size_t)(by * 8 + bx) * 65536 + w * 8192 + lane * 4;
#pragma unroll
  for (int i = 0; i < 8; ++i)
#pragma unroll
    for (int j = 0; j < 4; ++j) {
      ushort4v o;
#pragma unroll
      for (int r = 0; r < 4; ++r) o[r] = f2bf(acc[i][j][r]);
      *(ushort4v*)&cp[(i * 4 + j) * 256] = o;
    }
#undef STAGE_A
#undef STAGE_B
#undef LDA
#undef LDB
#undef TILE
}

// ---------- Pass 3: sum bf16 split partials, square, reduce ----------
__global__ void __launch_bounds__(256) reduce_squares(
    const unsigned short* __restrict__ Cpart, const float* __restrict__ lam,
    float* __restrict__ out) {
  const int NQ = (D_DIM * D_DIM) / 8;            // ushort8 chunks per split
  const ushort8* c = (const ushort8*)Cpart;
  float s = 0.f;
  for (int idx = blockIdx.x * 256 + threadIdx.x; idx < NQ; idx += gridDim.x * 256) {
    float v[8];
#pragma unroll
    for (int j = 0; j < 8; ++j) v[j] = 0.f;
#pragma unroll
    for (int z = 0; z < SPLITK; ++z) {
      ushort8 u = c[(size_t)z * NQ + idx];
#pragma unroll
      for (int j = 0; j < 8; ++j) v[j] += bf2f(u[j]);
    }
#pragma unroll
    for (int j = 0; j < 8; ++j) s += v[j] * v[j];
  }
  for (int off = 32; off > 0; off >>= 1) s += __shfl_down(s, off, 64);
  __shared__ float red[4];
  const int wave = threadIdx.x >> 6, lane = threadIdx.x & 63;
  if (lane == 0) red[wave] = s;
  __syncthreads();
  if (threadIdx.x == 0) atomicAdd(out, (red[0] + red[1] + red[2] + red[3]) * lam[0]);
}

// ---------- Fallback (only if ws too small): correct, slow ----------
__global__ void __launch_bounds__(256) fallback_kernel(
    const float* __restrict__ F, const float* __restrict__ Fs,
    const float* __restrict__ lam, float* __restrict__ out) {
  __shared__ float sA[64][16], sB[64][16];
  const int d0 = blockIdx.y * 16, e0 = blockIdx.x * 16;
  const int t = threadIdx.x;
  const int td = t >> 4, te = t & 15;
  float s = 0.f;
  for (int k0 = 0; k0 < N_ROWS; k0 += 64) {
#pragma unroll
    for (int p = 0; p < 4; ++p) {
      const int k = (t >> 4) + p * 16;
      const int cc = t & 15;
      sA[k][cc] = F[(size_t)(k0 + k) * D_DIM + d0 + cc];
      sB[k][cc] = Fs[(size_t)(k0 + k) * D_DIM + e0 + cc];
    }
    __syncthreads();
#pragma unroll
    for (int kk = 0; kk < 64; ++kk) s += sA[kk][td] * sB[kk][te];
    __syncthreads();
  }
  float q = s * s;
  for (int off = 32; off > 0; off >>= 1) q += __shfl_down(q, off, 64);
  __shared__ float red[4];
  if ((t & 63) == 0) red[t >> 6] = q;
  __syncthreads();
  if (t == 0) atomicAdd(out, (red[0] + red[1] + red[2] + red[3]) * lam[0]);
}

extern "C" void kernel_launch(void* const* d_in, const int* in_sizes, int n_in,
                              void* d_out, int out_size, void* d_ws, size_t ws_size,
                              hipStream_t stream) {
  const float* F   = (const float*)d_in[0];
  const float* Fs  = (const float*)d_in[1];
  const float* lam = (const float*)d_in[2];
  float* out = (float*)d_out;
  hipMemsetAsync(d_out, 0, sizeof(float) * (size_t)out_size, stream);

  const size_t bf_bytes = (size_t)NP * NS * 8192;                 // 64 MB per packed matrix
  const size_t cpart_bytes = (size_t)SPLITK * D_DIM * D_DIM * 2;  // 32 MB (bf16 partials)
  const size_t need = 2 * bf_bytes + cpart_bytes;                 // 160 MB

  if (ws_size >= need) {
    unsigned short* Fb  = (unsigned short*)d_ws;
    unsigned short* Fsb = Fb + bf_bytes / 2;
    unsigned short* Cpart = (unsigned short*)((char*)d_ws + 2 * bf_bytes);
    transpose_pack<<<dim3(N_ROWS / 64, 2), 256, 0, stream>>>(F, Fs, Fb, Fsb);
    gemm_packed<<<dim3(8, 8, SPLITK), 512, 0, stream>>>(Fb, Fsb, Cpart);
    reduce_squares<<<dim3(1024), 256, 0, stream>>>(Cpart, lam, out);
  } else {
    fallback_kernel<<<dim3(128, 128), 256, 0, stream>>>(F, Fs, lam, out);
  }
}

// Round 5
// 415.470 us; speedup vs baseline: 1.3107x; 1.0471x over previous
//
#include <hip/hip_runtime.h>
#include <hip/hip_bf16.h>

// out = lambda * ||F^T F_star||_F^2,  F,F* fp32 [16384, 2048]
#define N_ROWS 16384
#define D_DIM  2048
#define SPLITK 4
#define NS     (N_ROWS / 32)     // 512 k-steps of 32
#define NP     (D_DIM / 128)     // 16 panels of 128 rows
#define NSS    (NS / SPLITK)     // 128 k-steps per split
#define NKT    (NSS / 2)         // 64 K-tiles (BK=64) per block

// Packed operand layout (bf16): chunk(m_panel, k_step) = 8192 B contiguous at
// ushort offset (m_panel*NS + k_step)*4096. Within a chunk, subtile tt (16 rows):
// offset(m,k) = tt*512 + (k>>3)*128 + (m&15)*8 + (k&7) for lane = (k>>3)<<4 | (m&15):
// the MFMA A/B fragment image. All LDS reads are linear 16B/lane -> conflict-free.

typedef __attribute__((ext_vector_type(8))) short short8;        // 8 bf16 (4 VGPRs)
typedef __attribute__((ext_vector_type(4))) float f32x4;         // MFMA acc
typedef __attribute__((ext_vector_type(8))) unsigned short ushort8;
typedef __attribute__((ext_vector_type(4))) unsigned short ushort4v;

#define GPTR(p) ((const __attribute__((address_space(1))) void*)(p))
#define LPTR(p) ((__attribute__((address_space(3))) void*)(p))

__device__ __forceinline__ unsigned short f2bf(float x) {
  __hip_bfloat16 b = __float2bfloat16(x);
  return *reinterpret_cast<unsigned short*>(&b);
}
__device__ __forceinline__ float bf2f(unsigned short u) {
  unsigned int v = ((unsigned int)u) << 16;
  return *reinterpret_cast<float*>(&v);
}

// ---------- Pass 1: fp32[N][D] -> packed bf16 fragment image, LDS-bounced ----------
// Block = 1 k-step (32 rows) x 1024 cols. Phase A reads each row as ONE 4KB
// contiguous wave-sweep (DRAM page-local burst), converts, stages a linear
// [k][m] bf16 image in 64KB LDS. Phase B gathers the packed fragment image with
// ushort2 LDS reads (2-way = free) and writes full 8KB chunks. Grid (512,2,2).
__global__ void __launch_bounds__(256) transpose_pack(
    const float* __restrict__ F, const float* __restrict__ Fs,
    unsigned short* __restrict__ Fb, unsigned short* __restrict__ Fsb) {
  __shared__ unsigned short kl[32 * 1024];       // [k][m_local], 64 KB
  const float* src = blockIdx.z ? Fs : F;
  unsigned short* dst = blockIdx.z ? Fsb : Fb;
  const int t = threadIdx.x;
  const int ks = blockIdx.x;                     // k-step (32 rows)
  const int half = blockIdx.y;                   // which 1024-col half

  // Phase A: 32 rows, each row-half read as one contiguous 4KB sweep
  const float* sbase = src + (size_t)(ks * 32) * D_DIM + half * 1024 + t * 4;
#pragma unroll
  for (int k = 0; k < 32; ++k) {
    float4 v = *(const float4*)(sbase + (size_t)k * D_DIM);
    ushort4v o;
    o[0] = f2bf(v.x); o[1] = f2bf(v.y); o[2] = f2bf(v.z); o[3] = f2bf(v.w);
    *(ushort4v*)&kl[k * 1024 + t * 4] = o;       // ds_write_b64, 4-way (1.58x)
  }
  __syncthreads();

  // Phase B: emit packed image; ushort2-wide gathers (consecutive lanes -> 2-way, free)
  const unsigned int* kl32 = (const unsigned int*)kl;
#pragma unroll
  for (int q = 0; q < 2; ++q) {
    const int p = t + 256 * q;                   // m-pair index; m_local = 2p
    const int m0 = half * 1024 + 2 * p;          // even global col
    const int mt = m0 >> 7, tt = (m0 >> 4) & 7, mf = m0 & 15;
    unsigned short* ob = dst + ((size_t)mt * NS + ks) * 4096 + tt * 512 + mf * 8;
#pragma unroll
    for (int koct = 0; koct < 4; ++koct) {
      unsigned int r[8];
#pragma unroll
      for (int j = 0; j < 8; ++j) r[j] = kl32[(koct * 8 + j) * 512 + p];
      ushort8 oA, oB;                            // m0 and m0+1 rows of the image
      unsigned int* a32 = (unsigned int*)&oA;
      unsigned int* b32 = (unsigned int*)&oB;
#pragma unroll
      for (int i = 0; i < 4; ++i) {
        a32[i] = (r[2 * i] & 0xFFFFu) | (r[2 * i + 1] << 16);
        b32[i] = (r[2 * i] >> 16) | (r[2 * i + 1] & 0xFFFF0000u);
      }
      *(ushort8*)&ob[koct * 128] = oA;
      *(ushort8*)&ob[koct * 128 + 8] = oB;
    }
  }
}

// ---------- Pass 2: 256x256 tile, BK=64, 8 waves, 2-barrier/tile, A-chunk pipelined ----------
// LDS 128 KB (ushort units): A buf b panel p at b*16384 + p*8192
//                            B buf b panel q at 32768 + b*16384 + q*8192
// Register budget (2 waves/SIMD => 256 unified/wave): acc 128 AGPR + bAll 32
// + aR dbuf 32 + addressing ~ 248.
//
// Per K-tile T (buf B=T&1):
//   STAGE_A(T+1)->buf^1                      (region's readers drained last tile)
//   LDB all 8 (B resident) ; LDA chunk0 (4)
//   for c=0..3: [LDA chunk c+1 (4)] ; MFMA chunk c (16)
//   lgkmcnt(0) ; barrier                     (B(T) fully consumed -> WAR safe)
//   STAGE_B(T+2)->buf
//   vmcnt(4) ; barrier                       (A(T+1),B(T+1) landed; B(T+2) flying)
// vmcnt ledger at T's wait: B(T+1)4 + A(T+1)4 + B(T+2)4 = 12 outstanding,
// vmcnt(4) drains first 8 -> tile T+1 operands resident.
__global__ void __launch_bounds__(512, 2) gemm_packed(
    const unsigned short* __restrict__ Fb, const unsigned short* __restrict__ Fsb,
    unsigned short* __restrict__ Cpart) {
  __shared__ unsigned short lds[65536];          // 128 KB
  const int tid = threadIdx.x;
  const int w = tid >> 6, lane = tid & 63;
  const int wm = w >> 2, wn = w & 3;             // 2x4 waves, each owns 128x64 of C

  // XCD-aware bijective swizzle: each XCD gets 32 contiguous logical blocks =
  // 4 complete by-rows of one split (A panels + per-tile B slices stay in its L2).
  const int lin = blockIdx.x + (blockIdx.y << 3) + ((int)blockIdx.z << 6); // 0..255
  const int l   = (lin & 7) * 32 + (lin >> 3);
  const int bx = l & 7, by = (l >> 3) & 7, z = l >> 6;

  const size_t kbase = (size_t)z * NSS * 4096;   // this split's k-range (ushorts)
  size_t aSrc0 = ((size_t)(by * 2 + 0) * NS) * 4096 + kbase + (size_t)w * 1024 + lane * 8;
  size_t aSrc1 = ((size_t)(by * 2 + 1) * NS) * 4096 + kbase + (size_t)w * 1024 + lane * 8;
  size_t bSrc0 = ((size_t)(bx * 2 + 0) * NS) * 4096 + kbase + (size_t)w * 1024 + lane * 8;
  size_t bSrc1 = ((size_t)(bx * 2 + 1) * NS) * 4096 + kbase + (size_t)w * 1024 + lane * 8;

  const int aRd = wm * 8192 + lane * 8;                          // A frag base (ushorts)
  const int bRd = (wn >> 1) * 8192 + (wn & 1) * 2048 + lane * 8; // B frag base

#define STAGE_A(KT, P, BUF) do {                                               \
    int _kt = (KT); if (_kt >= NKT) _kt -= NKT;                                \
    const unsigned short* _s = Fb + (P ? aSrc1 : aSrc0) + (size_t)_kt * 8192;  \
    unsigned short* _d = &lds[(BUF) * 16384 + (P) * 8192 + w * 1024];          \
    __builtin_amdgcn_global_load_lds(GPTR(_s),       LPTR(_d),       16, 0, 0);\
    __builtin_amdgcn_global_load_lds(GPTR(_s + 512), LPTR(_d + 512), 16, 0, 0);\
  } while (0)
#define STAGE_B(KT, Q, BUF) do {                                               \
    int _kt = (KT); if (_kt >= NKT) _kt -= NKT;                                \
    const unsigned short* _s = Fsb + (Q ? bSrc1 : bSrc0) + (size_t)_kt * 8192; \
    unsigned short* _d = &lds[32768 + (BUF) * 16384 + (Q) * 8192 + w * 1024];  \
    __builtin_amdgcn_global_load_lds(GPTR(_s),       LPTR(_d),       16, 0, 0);\
    __builtin_amdgcn_global_load_lds(GPTR(_s + 512), LPTR(_d + 512), 16, 0, 0);\
  } while (0)
#define LDA(DST, BUF, I, SL) (DST) = *(const short8*)&lds[(BUF) * 16384 + aRd + (SL) * 4096 + (I) * 512]
#define LDB(DST, BUF, J, SL) (DST) = *(const short8*)&lds[32768 + (BUF) * 16384 + bRd + (SL) * 4096 + (J) * 512]

  f32x4 acc[8][4];
#pragma unroll
  for (int i = 0; i < 8; ++i)
#pragma unroll
    for (int j = 0; j < 4; ++j) acc[i][j] = 0.f;

  short8 bAll[4][2];        // B resident: 32 VGPRs
  short8 aR[2][2][2];       // A chunk double-buffer [buf][row][sl]: 32 VGPRs

  // prologue: tile 0 (A+B) into buf0, tile 1's B into buf1 (A(1) staged in tile 0)
  STAGE_A(0, 0, 0); STAGE_A(0, 1, 0);
  STAGE_B(0, 0, 0); STAGE_B(0, 1, 0);
  STAGE_B(1, 0, 1); STAGE_B(1, 1, 1);
  asm volatile("s_waitcnt vmcnt(4)" ::: "memory");   // tile 0 landed; B(1) may fly
  __builtin_amdgcn_s_barrier();
  asm volatile("" ::: "memory");

#define TILE(T, B) do {                                                        \
    STAGE_A((T) + 1, 0, (B) ^ 1);                                              \
    STAGE_A((T) + 1, 1, (B) ^ 1);                                              \
    _Pragma("unroll") for (int j = 0; j < 4; ++j) {                            \
      LDB(bAll[j][0], B, j, 0); LDB(bAll[j][1], B, j, 1); }                    \
    LDA(aR[0][0][0], B, 0, 0); LDA(aR[0][0][1], B, 0, 1);                      \
    LDA(aR[0][1][0], B, 1, 0); LDA(aR[0][1][1], B, 1, 1);                      \
    _Pragma("unroll") for (int c = 0; c < 4; ++c) {                            \
      if (c < 3) {                                                             \
        LDA(aR[(c + 1) & 1][0][0], B, 2 * c + 2, 0);                           \
        LDA(aR[(c + 1) & 1][0][1], B, 2 * c + 2, 1);                           \
        LDA(aR[(c + 1) & 1][1][0], B, 2 * c + 3, 0);                           \
        LDA(aR[(c + 1) & 1][1][1], B, 2 * c + 3, 1);                           \
      }                                                                        \
      __builtin_amdgcn_s_setprio(1);                                           \
      _Pragma("unroll") for (int sl = 0; sl < 2; ++sl)                         \
        _Pragma("unroll") for (int iw = 0; iw < 2; ++iw)                       \
          _Pragma("unroll") for (int j = 0; j < 4; ++j)                        \
            acc[2 * c + iw][j] = __builtin_amdgcn_mfma_f32_16x16x32_bf16(      \
                aR[c & 1][iw][sl], bAll[j][sl], acc[2 * c + iw][j], 0, 0, 0);  \
      __builtin_amdgcn_s_setprio(0);                                           \
    }                                                                          \
    asm volatile("s_waitcnt lgkmcnt(0)" ::: "memory");                         \
    __builtin_amdgcn_s_barrier();                                              \
    asm volatile("" ::: "memory");                                             \
    STAGE_B((T) + 2, 0, B);                                                    \
    STAGE_B((T) + 2, 1, B);                                                    \
    asm volatile("s_waitcnt vmcnt(4)" ::: "memory");                           \
    __builtin_amdgcn_s_barrier();                                              \
    asm volatile("" ::: "memory");                                             \
  } while (0)

  for (int t = 0; t < NKT; t += 2) {
    TILE(t, 0);
    TILE(t + 1, 1);
  }

  // Frobenius norm is layout-invariant: dump partials flat, coalesced, bf16.
  unsigned short* cp = Cpart + (size_t)z * (D_DIM * D_DIM)
                     + (size_t)(by * 8 + bx) * 65536 + w * 8192 + lane * 4;
#pragma unroll
  for (int i = 0; i < 8; ++i)
#pragma unroll
    for (int j = 0; j < 4; ++j) {
      ushort4v o;
#pragma unroll
      for (int r = 0; r < 4; ++r) o[r] = f2bf(acc[i][j][r]);
      *(ushort4v*)&cp[(i * 4 + j) * 256] = o;
    }
#undef STAGE_A
#undef STAGE_B
#undef LDA
#undef LDB
#undef TILE
}

// ---------- Pass 3: sum bf16 split partials, square, reduce ----------
__global__ void __launch_bounds__(256) reduce_squares(
    const unsigned short* __restrict__ Cpart, const float* __restrict__ lam,
    float* __restrict__ out) {
  const int NQ = (D_DIM * D_DIM) / 8;            // ushort8 chunks per split
  const ushort8* c = (const ushort8*)Cpart;
  float s = 0.f;
  for (int idx = blockIdx.x * 256 + threadIdx.x; idx < NQ; idx += gridDim.x * 256) {
    float v[8];
#pragma unroll
    for (int j = 0; j < 8; ++j) v[j] = 0.f;
#pragma unroll
    for (int z = 0; z < SPLITK; ++z) {
      ushort8 u = c[(size_t)z * NQ + idx];
#pragma unroll
      for (int j = 0; j < 8; ++j) v[j] += bf2f(u[j]);
    }
#pragma unroll
    for (int j = 0; j < 8; ++j) s += v[j] * v[j];
  }
  for (int off = 32; off > 0; off >>= 1) s += __shfl_down(s, off, 64);
  __shared__ float red[4];
  const int wave = threadIdx.x >> 6, lane = threadIdx.x & 63;
  if (lane == 0) red[wave] = s;
  __syncthreads();
  if (threadIdx.x == 0) atomicAdd(out, (red[0] + red[1] + red[2] + red[3]) * lam[0]);
}

// ---------- Fallback (only if ws too small): correct, slow ----------
__global__ void __launch_bounds__(256) fallback_kernel(
    const float* __restrict__ F, const float* __restrict__ Fs,
    const float* __restrict__ lam, float* __restrict__ out) {
  __shared__ float sA[64][16], sB[64][16];
  const int d0 = blockIdx.y * 16, e0 = blockIdx.x * 16;
  const int t = threadIdx.x;
  const int td = t >> 4, te = t & 15;
  float s = 0.f;
  for (int k0 = 0; k0 < N_ROWS; k0 += 64) {
#pragma unroll
    for (int p = 0; p < 4; ++p) {
      const int k = (t >> 4) + p * 16;
      const int cc = t & 15;
      sA[k][cc] = F[(size_t)(k0 + k) * D_DIM + d0 + cc];
      sB[k][cc] = Fs[(size_t)(k0 + k) * D_DIM + e0 + cc];
    }
    __syncthreads();
#pragma unroll
    for (int kk = 0; kk < 64; ++kk) s += sA[kk][td] * sB[kk][te];
    __syncthreads();
  }
  float q = s * s;
  for (int off = 32; off > 0; off >>= 1) q += __shfl_down(q, off, 64);
  __shared__ float red[4];
  if ((t & 63) == 0) red[t >> 6] = q;
  __syncthreads();
  if (t == 0) atomicAdd(out, (red[0] + red[1] + red[2] + red[3]) * lam[0]);
}

extern "C" void kernel_launch(void* const* d_in, const int* in_sizes, int n_in,
                              void* d_out, int out_size, void* d_ws, size_t ws_size,
                              hipStream_t stream) {
  const float* F   = (const float*)d_in[0];
  const float* Fs  = (const float*)d_in[1];
  const float* lam = (const float*)d_in[2];
  float* out = (float*)d_out;
  hipMemsetAsync(d_out, 0, sizeof(float) * (size_t)out_size, stream);

  const size_t bf_bytes = (size_t)NP * NS * 8192;                 // 64 MB per packed matrix
  const size_t cpart_bytes = (size_t)SPLITK * D_DIM * D_DIM * 2;  // 32 MB (bf16 partials)
  const size_t need = 2 * bf_bytes + cpart_bytes;                 // 160 MB

  if (ws_size >= need) {
    unsigned short* Fb  = (unsigned short*)d_ws;
    unsigned short* Fsb = Fb + bf_bytes / 2;
    unsigned short* Cpart = (unsigned short*)((char*)d_ws + 2 * bf_bytes);
    transpose_pack<<<dim3(NS, 2, 2), 256, 0, stream>>>(F, Fs, Fb, Fsb);
    gemm_packed<<<dim3(8, 8, SPLITK), 512, 0, stream>>>(Fb, Fsb, Cpart);
    reduce_squares<<<dim3(1024), 256, 0, stream>>>(Cpart, lam, out);
  } else {
    fallback_kernel<<<dim3(128, 128), 256, 0, stream>>>(F, Fs, lam, out);
  }
}